// Round 2
// baseline (4112.719 us; speedup 1.0000x reference)
//
#include <hip/hip_runtime.h>
#include <hip/hip_bf16.h>

// Problem constants: B=64, S=512, E=512, H=512, V=32000, T=2, L=1
// Output depends ONLY on batch sample 63 (lstm_out[-1] == last batch element).

#define NB 64   // persistent blocks for the recurrence

// ---------------------------------------------------------------------------
// Kernel 1: xg[t][g] = sum_e emb[sent[63][t]][e] * W_ih[g][e] + b_ih[g]+b_hh[g]
// M=512 (t), N=2048 (g), K=512. Both operands K-major (NT GEMM).
// ---------------------------------------------------------------------------
__global__ __launch_bounds__(256) void xg_gemm_k(
    const int* __restrict__ sent, const float* __restrict__ emb,
    const float* __restrict__ W_ih, const float* __restrict__ b_ih,
    const float* __restrict__ b_hh, float* __restrict__ xg)
{
    __shared__ float As[16][65];   // [k][m]
    __shared__ float Bs[16][65];   // [k][n]
    __shared__ int aidx[64];
    const int tid = threadIdx.x;
    const int t0 = blockIdx.x * 64;
    const int n0 = blockIdx.y * 64;
    if (tid < 64) aidx[tid] = sent[63 * 512 + t0 + tid];
    __syncthreads();

    const int kk = tid & 15;   // k within tile
    const int mm = tid >> 4;   // 0..15
    const int tx = tid & 15, ty = tid >> 4;
    float acc[4][4] = {};

    for (int kb = 0; kb < 512; kb += 16) {
        #pragma unroll
        for (int j = 0; j < 4; j++) {
            int m = mm + j * 16;
            As[kk][m] = emb[(size_t)aidx[m] * 512 + kb + kk];
            Bs[kk][m] = W_ih[(size_t)(n0 + m) * 512 + kb + kk];
        }
        __syncthreads();
        #pragma unroll
        for (int k = 0; k < 16; k++) {
            float a[4], bv[4];
            #pragma unroll
            for (int i = 0; i < 4; i++) a[i] = As[k][ty * 4 + i];
            #pragma unroll
            for (int j = 0; j < 4; j++) bv[j] = Bs[k][tx * 4 + j];
            #pragma unroll
            for (int i = 0; i < 4; i++)
                #pragma unroll
                for (int j = 0; j < 4; j++)
                    acc[i][j] += a[i] * bv[j];
        }
        __syncthreads();
    }

    #pragma unroll
    for (int i = 0; i < 4; i++) {
        int t = t0 + ty * 4 + i;
        #pragma unroll
        for (int j = 0; j < 4; j++) {
            int col = n0 + tx * 4 + j;
            xg[(size_t)t * 2048 + col] = acc[i][j] + b_ih[col] + b_hh[col];
        }
    }
}

// ---------------------------------------------------------------------------
// Kernel 2: persistent batch-1 LSTM recurrence over 512 steps.
// 64 blocks x 256 threads. Block b owns h-indices [b*8, b*8+8) -> 32 gate rows
// {q*512 + b*8 + j : q in 0..3, j in 0..7}. W_hh slice lives in VGPRs
// (4 rows x 16 cols = 64 floats per thread).
//
// Handoff protocol (all data+flags via agent-scope atomics -> LLC coherence
// point; no reliance on per-XCD L2 writeback/invalidate):
//   writer: atomic-store 8 h values -> __threadfence (s_waitcnt: stores are AT
//           the LLC) -> atomic-store flag[t][b]=1
//   reader: lane i of wave 0 polls flag[t-1][i] (relaxed, one coalesced load
//           per iteration, per-lane exec exit) -> __syncthreads -> stage
//           h_{t-1} via relaxed agent atomic loads (read LLC directly).
// flag=1 visible at LLC  =>  h data already at LLC  =>  reads see it.
// ---------------------------------------------------------------------------
__global__ __launch_bounds__(256, 1) void lstm_seq_k(
    const float* __restrict__ h0, const float* __restrict__ c0,
    const float* __restrict__ W_hh, const float* __restrict__ xg,
    float* __restrict__ hs, unsigned int* __restrict__ flags)
{
    __shared__ float hbuf[512];
    __shared__ float gacc[32];
    __shared__ float cbuf[8];

    const int tid = threadIdx.x;
    const int b = blockIdx.x;
    const int cg = tid & 31;   // column group: 16 cols each, 32 groups = 512
    const int rg = tid >> 5;   // row group: 4 rows each, 8 groups = 32 rows

    // Global gate-row indices for this thread's 4 rows.
    int grow[4];
    #pragma unroll
    for (int r = 0; r < 4; r++) {
        int rl = rg * 4 + r;                    // row_local in [0,32)
        grow[r] = (rl >> 3) * 512 + b * 8 + (rl & 7);
    }

    // Load weight slice into registers: 16 float4 = 64 VGPRs.
    float4 wv[4][4];
    #pragma unroll
    for (int r = 0; r < 4; r++)
        #pragma unroll
        for (int cq = 0; cq < 4; cq++)
            wv[r][cq] = *(const float4*)&W_hh[(size_t)grow[r] * 512 + cg * 16 + cq * 4];

    // Init cell state for this block's 8 h-indices. (L=1, sample 63)
    if (tid < 8) cbuf[tid] = c0[63 * 512 + b * 8 + tid];
    __syncthreads();

    for (int t = 0; t < 512; t++) {
        // Prefetch xg for this step (independent of h -> overlaps the wait).
        float xgp[4];
        if (cg == 0) {
            #pragma unroll
            for (int r = 0; r < 4; r++)
                xgp[r] = xg[(size_t)t * 2048 + grow[r]];
        }

        const float* hsrc = (t == 0) ? (h0 + 63 * 512) : (hs + (size_t)(t - 1) * 512);

        if (t > 0) {
            if (tid < 64) {
                unsigned int* fp = &flags[(size_t)(t - 1) * 64 + tid];
                while (__hip_atomic_load(fp, __ATOMIC_RELAXED,
                                         __HIP_MEMORY_SCOPE_AGENT) == 0u) { }
            }
        }
        __syncthreads();

        // Stage h_{t-1} into LDS straight from the LLC.
        {
            float* p0 = const_cast<float*>(&hsrc[tid]);
            float* p1 = const_cast<float*>(&hsrc[tid + 256]);
            hbuf[tid]       = __hip_atomic_load(p0, __ATOMIC_RELAXED, __HIP_MEMORY_SCOPE_AGENT);
            hbuf[tid + 256] = __hip_atomic_load(p1, __ATOMIC_RELAXED, __HIP_MEMORY_SCOPE_AGENT);
        }
        __syncthreads();

        // 4 rows x 16 cols of FMA per thread.
        float4 hv[4];
        #pragma unroll
        for (int cq = 0; cq < 4; cq++)
            hv[cq] = *(const float4*)&hbuf[cg * 16 + cq * 4];

        float acc[4];
        #pragma unroll
        for (int r = 0; r < 4; r++) {
            float s = 0.f;
            #pragma unroll
            for (int cq = 0; cq < 4; cq++) {
                s += wv[r][cq].x * hv[cq].x;
                s += wv[r][cq].y * hv[cq].y;
                s += wv[r][cq].z * hv[cq].z;
                s += wv[r][cq].w * hv[cq].w;
            }
            acc[r] = s;
        }

        // Reduce over the 32 column-group lanes (xor masks <=16 stay in half-wave).
        #pragma unroll
        for (int r = 0; r < 4; r++) {
            #pragma unroll
            for (int m = 16; m >= 1; m >>= 1)
                acc[r] += __shfl_xor(acc[r], m, 64);
        }
        if (cg == 0) {
            #pragma unroll
            for (int r = 0; r < 4; r++)
                gacc[rg * 4 + r] = acc[r] + xgp[r];   // gacc index == q*8 + j
        }
        __syncthreads();

        // Gate tail on lanes 0..7 (wave 0). Torch order: i, f, g, o.
        if (tid < 8) {
            float gi = gacc[tid];
            float gf = gacc[8 + tid];
            float gc = gacc[16 + tid];
            float go = gacc[24 + tid];
            float ii = 1.f / (1.f + __expf(-gi));
            float ff = 1.f / (1.f + __expf(-gf));
            float cc = 1.f - 2.f / (__expf(2.f * gc) + 1.f);   // tanh
            float oo = 1.f / (1.f + __expf(-go));
            float cn = ff * cbuf[tid] + ii * cc;
            cbuf[tid] = cn;
            float th = 1.f - 2.f / (__expf(2.f * cn) + 1.f);   // tanh
            // Agent-scope atomic store: goes straight to the LLC.
            __hip_atomic_store(&hs[(size_t)t * 512 + b * 8 + tid], oo * th,
                               __ATOMIC_RELAXED, __HIP_MEMORY_SCOPE_AGENT);
        }

        // Drain stores to the LLC, then publish this block's per-step flag.
        __threadfence();
        if (tid == 0) {
            __hip_atomic_store(&flags[(size_t)t * 64 + b], 1u,
                               __ATOMIC_RELEASE, __HIP_MEMORY_SCOPE_AGENT);
        }
    }
}

// ---------------------------------------------------------------------------
// Kernel 3: out[s][u] = hs[s] . W_lin[u] + b_lin[u], S=512, T=2.
// One wave per s; both outputs per wave.
// ---------------------------------------------------------------------------
__global__ __launch_bounds__(256) void final_linear_k(
    const float* __restrict__ hs, const float* __restrict__ W_lin,
    const float* __restrict__ b_lin, float* __restrict__ out)
{
    const int tid = threadIdx.x;
    const int wave = tid >> 6;
    const int lane = tid & 63;
    const int s = blockIdx.x * 4 + wave;
    const float* h = hs + (size_t)s * 512;
    float a0 = 0.f, a1 = 0.f;
    #pragma unroll
    for (int k0 = 0; k0 < 512; k0 += 64) {
        float hv = h[k0 + lane];
        a0 += hv * W_lin[k0 + lane];
        a1 += hv * W_lin[512 + k0 + lane];
    }
    #pragma unroll
    for (int m = 32; m >= 1; m >>= 1) {
        a0 += __shfl_xor(a0, m, 64);
        a1 += __shfl_xor(a1, m, 64);
    }
    if (lane == 0) {
        out[s * 2]     = a0 + b_lin[0];
        out[s * 2 + 1] = a1 + b_lin[1];
    }
}

// ---------------------------------------------------------------------------
extern "C" void kernel_launch(void* const* d_in, const int* in_sizes, int n_in,
                              void* d_out, int out_size, void* d_ws, size_t ws_size,
                              hipStream_t stream)
{
    const int*   sent  = (const int*)d_in[0];     // [64,512] int32
    const float* h0    = (const float*)d_in[1];   // [1,64,512]
    const float* c0    = (const float*)d_in[2];   // [1,64,512]
    const float* emb   = (const float*)d_in[3];   // [32000,512]
    const float* W_ih  = (const float*)d_in[4];   // [2048,512]
    const float* W_hh  = (const float*)d_in[5];   // [2048,512]
    const float* b_ih  = (const float*)d_in[6];   // [2048]
    const float* b_hh  = (const float*)d_in[7];   // [2048]
    const float* W_lin = (const float*)d_in[8];   // [2,512]
    const float* b_lin = (const float*)d_in[9];   // [2]
    float* out = (float*)d_out;                   // [512,2]

    char* ws = (char*)d_ws;
    float* xg = (float*)ws;                                   // 4 MB: [512,2048]
    float* hs = (float*)(ws + 4 * 1024 * 1024);               // 1 MB: [512,512]
    unsigned int* flags = (unsigned int*)(ws + 5 * 1024 * 1024); // 128 KB: [512,64]

    // Zero the flags (workspace is poisoned 0xAA before every launch).
    hipMemsetAsync(flags, 0, 512 * 64 * sizeof(unsigned int), stream);

    dim3 g1(8, 32);
    xg_gemm_k<<<g1, 256, 0, stream>>>(sent, emb, W_ih, b_ih, b_hh, xg);
    lstm_seq_k<<<NB, 256, 0, stream>>>(h0, c0, W_hh, xg, hs, flags);
    final_linear_k<<<128, 256, 0, stream>>>(hs, W_lin, b_lin, out);
}

// Round 3
// 984.323 us; speedup vs baseline: 4.1782x; 4.1782x over previous
//
#include <hip/hip_runtime.h>
#include <hip/hip_bf16.h>

// Problem constants: B=64, S=512, E=512, H=512, V=32000, T=2, L=1
// Output depends ONLY on batch sample 63 (lstm_out[-1] == last batch element).

#define NB 64   // persistent blocks for the recurrence

// LDS h-buffer swizzle: 32 groups of 16 floats, padded to stride 20 words
// (80 B = 5 banks*16B) -> float4 reads stay 16B-aligned, 16-way conflict -> 4-way.
#define HIDX(e) ((((e) >> 4) * 20) + ((e) & 15))

// ---------------------------------------------------------------------------
// Kernel 1: xg[t][g] = sum_e emb[sent[63][t]][e] * W_ih[g][e] + b_ih[g]+b_hh[g]
// M=512 (t), N=2048 (g), K=512. Both operands K-major (NT GEMM).
// ---------------------------------------------------------------------------
__global__ __launch_bounds__(256) void xg_gemm_k(
    const int* __restrict__ sent, const float* __restrict__ emb,
    const float* __restrict__ W_ih, const float* __restrict__ b_ih,
    const float* __restrict__ b_hh, float* __restrict__ xg)
{
    __shared__ float As[16][65];   // [k][m]
    __shared__ float Bs[16][65];   // [k][n]
    __shared__ int aidx[64];
    const int tid = threadIdx.x;
    const int t0 = blockIdx.x * 64;
    const int n0 = blockIdx.y * 64;
    if (tid < 64) aidx[tid] = sent[63 * 512 + t0 + tid];
    __syncthreads();

    const int kk = tid & 15;   // k within tile
    const int mm = tid >> 4;   // 0..15
    const int tx = tid & 15, ty = tid >> 4;
    float acc[4][4] = {};

    for (int kb = 0; kb < 512; kb += 16) {
        #pragma unroll
        for (int j = 0; j < 4; j++) {
            int m = mm + j * 16;
            As[kk][m] = emb[(size_t)aidx[m] * 512 + kb + kk];
            Bs[kk][m] = W_ih[(size_t)(n0 + m) * 512 + kb + kk];
        }
        __syncthreads();
        #pragma unroll
        for (int k = 0; k < 16; k++) {
            float a[4], bv[4];
            #pragma unroll
            for (int i = 0; i < 4; i++) a[i] = As[k][ty * 4 + i];
            #pragma unroll
            for (int j = 0; j < 4; j++) bv[j] = Bs[k][tx * 4 + j];
            #pragma unroll
            for (int i = 0; i < 4; i++)
                #pragma unroll
                for (int j = 0; j < 4; j++)
                    acc[i][j] += a[i] * bv[j];
        }
        __syncthreads();
    }

    #pragma unroll
    for (int i = 0; i < 4; i++) {
        int t = t0 + ty * 4 + i;
        #pragma unroll
        for (int j = 0; j < 4; j++) {
            int col = n0 + tx * 4 + j;
            xg[(size_t)t * 2048 + col] = acc[i][j] + b_ih[col] + b_hh[col];
        }
    }
}

// ---------------------------------------------------------------------------
// Kernel 2: persistent batch-1 LSTM recurrence, 512 steps, 64 blocks x 256.
// Block b owns h-indices [b*8, b*8+8) -> 32 gate rows {q*512 + b*8 + j}.
//
// Handoff: NO fences, NO flags. h values travel as tagged 64-bit slots
//   slot = (uint64)(t+1) << 32 | float_bits(h_t)
// stored with relaxed agent-scope 8B atomic stores (individually visible at
// the LLC). Readers poll the slots themselves — the poll IS the data read
// (1 LLC round-trip). Two slot arrays ping-pong by step parity; a writer can
// only overwrite a buffer after observing every consumer's tag from the
// previous step, and consumers publish tags only after reading that buffer,
// so the protocol is dependency-ordered race-free without any fence.
// Full history hs[t][i] is written with plain stores for the final linear
// (kernel-boundary release makes it visible).
// ---------------------------------------------------------------------------
__global__ __launch_bounds__(256, 1) void lstm_seq_k(
    const float* __restrict__ h0, const float* __restrict__ c0,
    const float* __restrict__ W_hh, const float* __restrict__ xg,
    float* __restrict__ hs,
    unsigned long long* __restrict__ sA,
    unsigned long long* __restrict__ sB)
{
    __shared__ float hbuf[32 * 20];
    __shared__ float gacc[32];
    __shared__ float cbuf[8];

    const int tid = threadIdx.x;
    const int b = blockIdx.x;
    const int cg = tid & 31;   // column group: 16 cols each
    const int rg = tid >> 5;   // row group: 4 rows each, 8 groups = 32 rows

    // Global gate-row indices for this thread's 4 rows.
    int grow[4];
    #pragma unroll
    for (int r = 0; r < 4; r++) {
        int rl = rg * 4 + r;                    // row_local in [0,32)
        grow[r] = (rl >> 3) * 512 + b * 8 + (rl & 7);
    }

    // Weight slice (compiler may register- or L2-cache it; no fences in the
    // loop anymore, so L2 stays warm either way).
    float4 wv[4][4];
    #pragma unroll
    for (int r = 0; r < 4; r++)
        #pragma unroll
        for (int cq = 0; cq < 4; cq++)
            wv[r][cq] = *(const float4*)&W_hh[(size_t)grow[r] * 512 + cg * 16 + cq * 4];

    if (tid < 8) cbuf[tid] = c0[63 * 512 + b * 8 + tid];
    __syncthreads();

    for (int t = 0; t < 512; t++) {
        // Prefetch xg for this step (independent of h -> overlaps the wait).
        float xgp[4];
        if (cg == 0) {
            #pragma unroll
            for (int r = 0; r < 4; r++)
                xgp[r] = xg[(size_t)t * 2048 + grow[r]];
        }

        if (t == 0) {
            hbuf[HIDX(tid)]       = h0[63 * 512 + tid];
            hbuf[HIDX(tid + 256)] = h0[63 * 512 + tid + 256];
        } else {
            // Poll tagged slots of step t-1 (tag == t) in buffer (t-1)&1.
            unsigned long long* src = ((t - 1) & 1) ? sB : sA;
            unsigned long long* p0 = &src[tid];
            unsigned long long* p1 = &src[tid + 256];
            const unsigned int expt = (unsigned int)t;
            unsigned long long v0, v1;
            for (;;) {
                v0 = __hip_atomic_load(p0, __ATOMIC_RELAXED, __HIP_MEMORY_SCOPE_AGENT);
                v1 = __hip_atomic_load(p1, __ATOMIC_RELAXED, __HIP_MEMORY_SCOPE_AGENT);
                if ((unsigned int)(v0 >> 32) == expt &&
                    (unsigned int)(v1 >> 32) == expt) break;
            }
            hbuf[HIDX(tid)]       = __uint_as_float((unsigned int)v0);
            hbuf[HIDX(tid + 256)] = __uint_as_float((unsigned int)v1);
        }
        __syncthreads();

        // 4 rows x 16 cols of FMA per thread.
        float4 hv[4];
        #pragma unroll
        for (int cq = 0; cq < 4; cq++)
            hv[cq] = *(const float4*)&hbuf[cg * 20 + cq * 4];

        float acc[4];
        #pragma unroll
        for (int r = 0; r < 4; r++) {
            float s = 0.f;
            #pragma unroll
            for (int cq = 0; cq < 4; cq++) {
                s += wv[r][cq].x * hv[cq].x;
                s += wv[r][cq].y * hv[cq].y;
                s += wv[r][cq].z * hv[cq].z;
                s += wv[r][cq].w * hv[cq].w;
            }
            acc[r] = s;
        }

        // Reduce over the 32 column-group lanes (xor masks <=16 stay in half-wave).
        #pragma unroll
        for (int r = 0; r < 4; r++) {
            #pragma unroll
            for (int m = 16; m >= 1; m >>= 1)
                acc[r] += __shfl_xor(acc[r], m, 64);
        }
        if (cg == 0) {
            #pragma unroll
            for (int r = 0; r < 4; r++)
                gacc[rg * 4 + r] = acc[r] + xgp[r];   // gacc index == q*8 + j
        }
        __syncthreads();

        // Gate tail on lanes 0..7 (wave 0). Torch order: i, f, g, o.
        if (tid < 8) {
            float gi = gacc[tid];
            float gf = gacc[8 + tid];
            float gc = gacc[16 + tid];
            float go = gacc[24 + tid];
            float ii = 1.f / (1.f + __expf(-gi));
            float ff = 1.f / (1.f + __expf(-gf));
            float cc = 1.f - 2.f / (__expf(2.f * gc) + 1.f);   // tanh
            float oo = 1.f / (1.f + __expf(-go));
            float cn = ff * cbuf[tid] + ii * cc;
            cbuf[tid] = cn;
            float th = 1.f - 2.f / (__expf(2.f * cn) + 1.f);   // tanh
            float hval = oo * th;

            // History for the final linear (plain store).
            hs[(size_t)t * 512 + b * 8 + tid] = hval;

            // Tagged slot: one 8B relaxed agent atomic store -> LLC.
            unsigned long long* dst = (t & 1) ? sB : sA;
            unsigned long long pv =
                ((unsigned long long)(unsigned int)(t + 1) << 32) |
                (unsigned long long)__float_as_uint(hval);
            __hip_atomic_store(&dst[b * 8 + tid], pv,
                               __ATOMIC_RELAXED, __HIP_MEMORY_SCOPE_AGENT);
        }
        // NO __threadfence, NO flag store.
    }
}

// ---------------------------------------------------------------------------
// Kernel 3: out[s][u] = hs[s] . W_lin[u] + b_lin[u], S=512, T=2.
// ---------------------------------------------------------------------------
__global__ __launch_bounds__(256) void final_linear_k(
    const float* __restrict__ hs, const float* __restrict__ W_lin,
    const float* __restrict__ b_lin, float* __restrict__ out)
{
    const int tid = threadIdx.x;
    const int wave = tid >> 6;
    const int lane = tid & 63;
    const int s = blockIdx.x * 4 + wave;
    const float* h = hs + (size_t)s * 512;
    float a0 = 0.f, a1 = 0.f;
    #pragma unroll
    for (int k0 = 0; k0 < 512; k0 += 64) {
        float hv = h[k0 + lane];
        a0 += hv * W_lin[k0 + lane];
        a1 += hv * W_lin[512 + k0 + lane];
    }
    #pragma unroll
    for (int m = 32; m >= 1; m >>= 1) {
        a0 += __shfl_xor(a0, m, 64);
        a1 += __shfl_xor(a1, m, 64);
    }
    if (lane == 0) {
        out[s * 2]     = a0 + b_lin[0];
        out[s * 2 + 1] = a1 + b_lin[1];
    }
}

// ---------------------------------------------------------------------------
extern "C" void kernel_launch(void* const* d_in, const int* in_sizes, int n_in,
                              void* d_out, int out_size, void* d_ws, size_t ws_size,
                              hipStream_t stream)
{
    const int*   sent  = (const int*)d_in[0];     // [64,512] int32
    const float* h0    = (const float*)d_in[1];   // [1,64,512]
    const float* c0    = (const float*)d_in[2];   // [1,64,512]
    const float* emb   = (const float*)d_in[3];   // [32000,512]
    const float* W_ih  = (const float*)d_in[4];   // [2048,512]
    const float* W_hh  = (const float*)d_in[5];   // [2048,512]
    const float* b_ih  = (const float*)d_in[6];   // [2048]
    const float* b_hh  = (const float*)d_in[7];   // [2048]
    const float* W_lin = (const float*)d_in[8];   // [2,512]
    const float* b_lin = (const float*)d_in[9];   // [2]
    float* out = (float*)d_out;                   // [512,2]

    char* ws = (char*)d_ws;
    float* xg = (float*)ws;                                   // 4 MB: [512,2048]
    float* hs = (float*)(ws + 4 * 1024 * 1024);               // 1 MB: [512,512]
    unsigned long long* sA = (unsigned long long*)(ws + 5 * 1024 * 1024);          // 4 KB
    unsigned long long* sB = (unsigned long long*)(ws + 5 * 1024 * 1024 + 4096);   // 4 KB

    // Clear slot tags (0 != any expected tag 1..512). Poison 0xAA.. would also
    // be an invalid tag, but don't rely on it.
    hipMemsetAsync(sA, 0, 2 * 4096, stream);

    dim3 g1(8, 32);
    xg_gemm_k<<<g1, 256, 0, stream>>>(sent, emb, W_ih, b_ih, b_hh, xg);
    lstm_seq_k<<<NB, 256, 0, stream>>>(h0, c0, W_hh, xg, hs, sA, sB);
    final_linear_k<<<128, 256, 0, stream>>>(hs, W_lin, b_lin, out);
}